// Round 1
// baseline (377.551 us; speedup 1.0000x reference)
//
#include <hip/hip_runtime.h>
#include <hip/hip_cooperative_groups.h>

namespace cg = cooperative_groups;

typedef __bf16 bf16;
typedef bf16 bf16x8 __attribute__((ext_vector_type(8)));
typedef bf16 bf16x4 __attribute__((ext_vector_type(4)));
typedef float f32x4 __attribute__((ext_vector_type(4)));

#define MFMA16(a,b,c) __builtin_amdgcn_mfma_f32_16x16x32_bf16(a,b,c,0,0,0)

__device__ inline f32x4 zero4() { f32x4 z; z[0]=0.f; z[1]=0.f; z[2]=0.f; z[3]=0.f; return z; }

#define HW 16384   // 128*128
#define NQ 4096    // positions per window

// ---- workspace layout (bytes) ----
constexpr size_t OFF_Q    = 4096;                              // bf16 (4,4096,64)  2 MB  (row-major)
constexpr size_t OFF_QT   = OFF_Q  + (size_t)2097152;          // bf16 (4,64,4096)  2 MB  (Q^T)
constexpr size_t OFF_VT   = OFF_QT + (size_t)2097152;          // bf16 (4,64,4096)  2 MB
constexpr size_t OFF_MF   = OFF_VT + (size_t)2097152;          // fp32 (4,80,80) final M (atomic acc)
constexpr size_t OFF_T    = OFF_MF + (size_t)131072;           // bf16 HWC 2 MB
constexpr size_t OFF_T2   = OFF_T  + (size_t)2097152;          // bf16 HWC 2 MB
constexpr size_t OFF_W1   = OFF_T2 + (size_t)2097152;          // bf16 (9,64,64)
constexpr size_t OFF_W2   = OFF_W1 + 73728;
constexpr size_t OFF_W3   = OFF_W2 + 73728;                    // bf16 (64,64)
constexpr size_t OFF_WL   = OFF_W3 + 8192;                     // bf16 (64,64) convl weight

// per-phase LDS layouts, unioned (max = phase-2's exact 65536 B -> 2 blocks/CU)
struct SM0 { float xs[32][65]; float wl[4096]; bf16 qts[64][34]; };   // 29056 B
struct SM2 { bf16 Msl[4][80][88]; bf16 As[64][72]; };                 // 65536 B
struct SM3 { bf16 wsl[9][32][72]; };                                  // 41472 B
struct SM4 { bf16 As[32][72]; };                                      //  4608 B
union SMU { SM0 s0; SM2 s2; SM3 s3; SM4 s4; };

__global__ __launch_bounds__(256, 2) void k_fused(
    const float* __restrict__ x,   const float* __restrict__ unet,
    const float* __restrict__ wqk,
    const float* __restrict__ w1,  const float* __restrict__ c1b,
    const float* __restrict__ w2,  const float* __restrict__ c2b,
    const float* __restrict__ w3,  const float* __restrict__ c3b,
    const float* __restrict__ wlc, const float* __restrict__ clb,
    float* __restrict__ out,
    bf16* __restrict__ Q,  bf16* __restrict__ Qt, bf16* __restrict__ Vt,
    float* __restrict__ Mf, bf16* __restrict__ T, bf16* __restrict__ T2,
    bf16* __restrict__ W1, bf16* __restrict__ W2, bf16* __restrict__ W3,
    bf16* __restrict__ WLb)
{
    cg::grid_group grid = cg::this_grid();
    __shared__ __align__(16) SMU sm;
    int t = threadIdx.x, bx = blockIdx.x;

    // ================= phase 0: Q/Qt/Vt + weight prep + Mf zero (all 512 blocks) =================
    // weight prep: folded from old blocks 512..831 — exactly 1 element per thread of blocks 0..319
    if (bx < 320) {
        int g = bx * 256 + t;    // g in [0, 81920)
        if (g < 36864) {
            int tap = g >> 12, co = (g >> 6) & 63, ci = g & 63;
            W1[g] = (bf16)w1[(co*64 + ci)*9 + tap];
        } else if (g < 73728) {
            int d = g - 36864;
            int tap = d >> 12, co = (d >> 6) & 63, ci = d & 63;
            W2[d] = (bf16)w2[(co*64 + ci)*9 + tap];
        } else if (g < 77824) {
            int d = g - 73728;
            W3[d] = (bf16)w3[d];
        } else {
            int d = g - 77824;
            WLb[d] = (bf16)wlc[(d >> 6)*65 + (d & 63)];
        }
    }
    if (bx < 25) {     // zero the atomic M accumulator (25600 floats)
        int i = bx*1024 + t*4;
        if (i < 25600) {
            float4 z; z.x = 0.f; z.y = 0.f; z.z = 0.f; z.w = 0.f;
            *(float4*)(Mf + i) = z;
        }
    }
    {
        int y = bx >> 2, x0 = (bx & 3) * 32;

        // load 32 pixels x 64 channels; write Vt on the way (vectorized even/odd stores)
        {
            int c = t >> 2, seg = t & 3;
            const float4* xp = (const float4*)(x + (size_t)c*HW + y*128 + x0 + seg*8);
            float f[8];
            float4 v0 = xp[0], v1 = xp[1];
            f[0]=v0.x; f[1]=v0.y; f[2]=v0.z; f[3]=v0.w;
            f[4]=v1.x; f[5]=v1.y; f[6]=v1.z; f[7]=v1.w;
            #pragma unroll
            for (int k = 0; k < 8; ++k) sm.s0.xs[seg*8 + k][c] = f[k];
            int dh = y & 1;
            int base_n = (y >> 1)*64 + ((x0 + seg*8) >> 1);
            bf16x4 ve, vo;
            #pragma unroll
            for (int j = 0; j < 4; ++j) { ve[j] = (bf16)f[2*j]; vo[j] = (bf16)f[2*j+1]; }
            *(bf16x4*)(Vt + ((size_t)((dh*2 + 0)*64 + c))*NQ + base_n) = ve;
            *(bf16x4*)(Vt + ((size_t)((dh*2 + 1)*64 + c))*NQ + base_n) = vo;
        }
        // load wqk (64x64 fp32)
        {
            const float4* wp = (const float4*)wqk;
            #pragma unroll
            for (int k = 0; k < 4; ++k) {
                float4 v = wp[t*4 + k];
                sm.s0.wl[t*16 + k*4 + 0] = v.x; sm.s0.wl[t*16 + k*4 + 1] = v.y;
                sm.s0.wl[t*16 + k*4 + 2] = v.z; sm.s0.wl[t*16 + k*4 + 3] = v.w;
            }
        }
        __syncthreads();

        int p = t >> 3, eg = t & 7;
        float acc[8];
        #pragma unroll
        for (int k = 0; k < 8; ++k) acc[k] = 0.f;
        for (int c = 0; c < 64; ++c) {
            float xv = sm.s0.xs[p][c];
            const float* wr = &sm.s0.wl[c*64 + eg*8];
            #pragma unroll
            for (int k = 0; k < 8; ++k) acc[k] += xv * wr[k];
        }
        float ss = 0.f;
        #pragma unroll
        for (int k = 0; k < 8; ++k) ss += acc[k]*acc[k];
        ss += __shfl_xor(ss, 1);
        ss += __shfl_xor(ss, 2);
        ss += __shfl_xor(ss, 4);
        float inv = 1.f / (sqrtf(ss) + 1e-8f);

        int xp2 = x0 + p;
        int b2 = (y & 1)*2 + (xp2 & 1);
        int nidx = (y >> 1)*64 + (xp2 >> 1);
        bf16x8 qv;
        #pragma unroll
        for (int k = 0; k < 8; ++k) qv[k] = (bf16)(acc[k]*inv);
        *(bf16x8*)(Q + ((size_t)b2*NQ + nidx)*64 + eg*8) = qv;
        #pragma unroll
        for (int k = 0; k < 8; ++k) sm.s0.qts[eg*8 + k][p] = qv[k];
        __syncthreads();

        // transpose write: Q^T[b2][e][n]
        {
            int e = t >> 2, par = (t >> 1) & 1, seg2 = t & 1;
            int b2w = (y & 1)*2 + par;
            int nbase = (y >> 1)*64 + (x0 >> 1) + seg2*8;
            bf16x8 qt;
            #pragma unroll
            for (int j = 0; j < 8; ++j) qt[j] = sm.s0.qts[e][par + 2*(seg2*8 + j)];
            *(bf16x8*)(Qt + ((size_t)b2w*64 + e)*NQ + nbase) = qt;
        }
    }

    grid.sync();

    // ================= phase 1: M = [V|1]^T [Qhat|1] (blocks 0..63) =================
    if (bx < 64) {
        int b2 = bx & 3, kc = bx >> 2;     // kc 0..15
        int w = t >> 6, lane = t & 63, q = lane >> 4, l15 = lane & 15;
        const bf16* Vb  = Vt + (size_t)b2*64*NQ;
        const bf16* Qtb = Qt + (size_t)b2*64*NQ;
        bf16x8 onesfrag = {};
        if (l15 == 0) {
            #pragma unroll
            for (int k = 0; k < 8; ++k) onesfrag[k] = (bf16)1.0f;
        }
        f32x4 acc[5], acc1[5];
        #pragma unroll
        for (int nt = 0; nt < 5; ++nt) { acc[nt] = zero4(); acc1[nt] = zero4(); }

        int k0 = kc*256 + q*8;
        for (int it = 0; it < 8; ++it) {
            int kk = k0 + it*32;
            bf16x8 av = *(const bf16x8*)(Vb + (size_t)(w*16 + l15)*NQ + kk);
            bf16x8 b[5];
            #pragma unroll
            for (int nt = 0; nt < 4; ++nt) b[nt] = *(const bf16x8*)(Qtb + (size_t)(nt*16 + l15)*NQ + kk);
            b[4] = onesfrag;                               // col 64 = ones (c0 / m1)
            #pragma unroll
            for (int nt = 0; nt < 5; ++nt) {
                acc[nt] = MFMA16(av, b[nt], acc[nt]);
                if (w == 0) acc1[nt] = MFMA16(onesfrag, b[nt], acc1[nt]);  // row 64 = colsums
            }
        }
        float* mp = Mf + (size_t)b2*6400;
        #pragma unroll
        for (int nt = 0; nt < 5; ++nt)
            #pragma unroll
            for (int r = 0; r < 4; ++r)
                if (nt < 4 || l15 == 0)
                    unsafeAtomicAdd(&mp[(w*16 + q*4 + r)*80 + nt*16 + l15], acc[nt][r]);
        if (w == 0 && q == 0) {
            #pragma unroll
            for (int nt = 0; nt < 5; ++nt)
                if (nt < 4 || l15 == 0)
                    unsafeAtomicAdd(&mp[64*80 + nt*16 + l15], acc1[nt][0]);
        }
    }

    grid.sync();

    // ================= phase 2: gemm2 (attn tile) + convl + x -> T (blocks 0..255) =================
    if (bx < 256) {
        int p0 = bx * 64;

        #pragma unroll
        for (int ii = 0; ii < 25; ++ii) {
            int i = ii*1024 + t*4;
            float4 v = *(const float4*)(Mf + i);
            int b2i = i / 6400, rem = i - b2i*6400;
            int rr = rem / 80, cc = rem - rr*80;
            bf16x4 pk; pk[0] = (bf16)v.x; pk[1] = (bf16)v.y; pk[2] = (bf16)v.z; pk[3] = (bf16)v.w;
            *(bf16x4*)&sm.s2.Msl[b2i][rr][cc] = pk;
        }
        __syncthreads();

        int w = t >> 6, lane = t & 63, q = lane >> 4, l15 = lane & 15;
        {   // stage 1: attn tile. wave w = window b2; A rows n = m*256 + bx (m = l15)
            int b2 = w;
            const bf16* qp = Q + ((size_t)b2*NQ + l15*256 + bx)*64 + q*8;
            bf16x8 a0 = *(const bf16x8*)qp;
            bf16x8 a1 = *(const bf16x8*)(qp + 32);
            f32x4 acc[5];
            #pragma unroll
            for (int ct = 0; ct < 5; ++ct) {
                bf16x8 bf0 = *(const bf16x8*)&sm.s2.Msl[b2][ct*16 + l15][q*8];
                bf16x8 bf1 = *(const bf16x8*)&sm.s2.Msl[b2][ct*16 + l15][32 + q*8];
                f32x4 s = MFMA16(a0, bf0, zero4());
                acc[ct] = MFMA16(a1, bf1, s);
            }
            float c0v[4];
            #pragma unroll
            for (int ct = 0; ct < 4; ++ct) c0v[ct] = (float)sm.s2.Msl[b2][ct*16 + l15][64];
            #pragma unroll
            for (int r = 0; r < 4; ++r) {
                float ldot = __shfl(acc[4][r], lane & 48);
                float rl = 1.0f / fmaf(ldot, 0.125f, 4096.0f);
                #pragma unroll
                for (int ct = 0; ct < 4; ++ct)
                    sm.s2.As[ct*16 + l15][b2*16 + q*4 + r] = (bf16)(fmaf(acc[ct][r], 0.125f, c0v[ct]) * rl);
            }
        }
        __syncthreads();

        // stage 2: convl — wave w = px-block (n = w*16+l15); co in regs, contiguous bf16x4 stores
        int px = w*16 + l15;
        bf16x8 b0 = *(const bf16x8*)&sm.s2.As[px][q*8];
        bf16x8 b1 = *(const bf16x8*)&sm.s2.As[px][32 + q*8];
        float u = unet[p0 + px];
        #pragma unroll
        for (int mt = 0; mt < 4; ++mt) {
            const bf16* ap = WLb + (size_t)(mt*16 + l15)*64 + q*8;
            bf16x8 a0 = *(const bf16x8*)ap;
            bf16x8 a1 = *(const bf16x8*)(ap + 32);
            f32x4 s = MFMA16(a0, b0, zero4());
            f32x4 o = MFMA16(a1, b1, s);
            bf16x4 st;
            #pragma unroll
            for (int r = 0; r < 4; ++r) {
                int co = mt*16 + q*4 + r;
                float v = o[r] + u*wlc[co*65 + 64] + clb[co] + x[(size_t)co*HW + p0 + px];
                st[r] = (bf16)v;
            }
            *(bf16x4*)(T + (size_t)(p0 + px)*64 + mt*16 + q*4) = st;
        }
    }

    grid.sync();

    // ================= phase 3: conv1 3x3 dil1 + bias + relu (all 512 blocks) =================
    {
        int y = bx >> 2, xh = (bx >> 1) & 1, coh = bx & 1;
        int w = t >> 6, lane = t & 63, q = lane >> 4, l15 = lane & 15;
        int xb = xh*64 + w*16;

        for (int i = t; i < 2304; i += 256) {
            int tap = i >> 8, rem = i & 255, co = rem >> 3, k8 = (rem & 7) * 8;
            *(bf16x8*)&sm.s3.wsl[tap][co][k8] =
                *(const bf16x8*)(W1 + (((size_t)(tap*64 + coh*32 + co)) << 6) + k8);
        }
        __syncthreads();

        f32x4 o[2];
        o[0] = zero4(); o[1] = zero4();
        #pragma unroll
        for (int ky = 0; ky < 3; ++ky) {
            int yy = y + (ky - 1);
            bool yok = (yy >= 0) && (yy < 128);
            #pragma unroll
            for (int kx = 0; kx < 3; ++kx) {
                int xx = xb + l15 + (kx - 1);
                bool ok = yok && (xx >= 0) && (xx < 128);
                bf16x8 alo = {}, ahi = {};
                if (ok) {
                    const bf16* ip = T + (size_t)(yy*128 + xx)*64 + q*8;
                    alo = *(const bf16x8*)ip;
                    ahi = *(const bf16x8*)(ip + 32);
                }
                int tap = ky*3 + kx;
                #pragma unroll
                for (int ct = 0; ct < 2; ++ct) {
                    bf16x8 blo = *(const bf16x8*)&sm.s3.wsl[tap][ct*16 + l15][q*8];
                    bf16x8 bhi = *(const bf16x8*)&sm.s3.wsl[tap][ct*16 + l15][32 + q*8];
                    o[ct] = MFMA16(alo, blo, o[ct]);
                    o[ct] = MFMA16(ahi, bhi, o[ct]);
                }
            }
        }
        #pragma unroll
        for (int ct = 0; ct < 2; ++ct) {
            int co = coh*32 + ct*16 + l15;
            float bias = c1b[co];
            #pragma unroll
            for (int r = 0; r < 4; ++r) {
                float v = fmaxf(o[ct][r] + bias, 0.f);
                T2[(size_t)(y*128 + xb + q*4 + r)*64 + co] = (bf16)v;
            }
        }
    }

    grid.sync();

    // ================= phase 4: conv2 (3x3 dil2, relu) + conv3 (1x1) + x -> out (all 512 blocks) =================
    {
        int y = bx >> 2, xq = bx & 3;
        int w = t >> 6, lane = t & 63, q = lane >> 4, l15 = lane & 15;
        int pxg = w & 1, coh = w >> 1;
        int xb = xq*32 + pxg*16;

        f32x4 o[2];
        o[0] = zero4(); o[1] = zero4();
        #pragma unroll
        for (int ky = 0; ky < 3; ++ky) {
            int yy = y + (ky - 1)*2;
            bool yok = (yy >= 0) && (yy < 128);
            #pragma unroll
            for (int kx = 0; kx < 3; ++kx) {
                int xx = xb + l15 + (kx - 1)*2;
                bool ok = yok && (xx >= 0) && (xx < 128);
                bf16x8 alo = {}, ahi = {};
                if (ok) {
                    const bf16* ip = T2 + (size_t)(yy*128 + xx)*64 + q*8;
                    alo = *(const bf16x8*)ip;
                    ahi = *(const bf16x8*)(ip + 32);
                }
                int tap = ky*3 + kx;
                #pragma unroll
                for (int ct = 0; ct < 2; ++ct) {
                    const bf16* wp = W2 + (size_t)(tap*64 + coh*32 + ct*16 + l15)*64 + q*8;
                    bf16x8 blo = *(const bf16x8*)wp;
                    bf16x8 bhi = *(const bf16x8*)(wp + 32);
                    o[ct] = MFMA16(alo, blo, o[ct]);
                    o[ct] = MFMA16(ahi, bhi, o[ct]);
                }
            }
        }
        #pragma unroll
        for (int ct = 0; ct < 2; ++ct) {
            int co = coh*32 + ct*16 + l15;
            float bias = c2b[co];
            #pragma unroll
            for (int r = 0; r < 4; ++r)
                sm.s4.As[pxg*16 + q*4 + r][co] = (bf16)fmaxf(o[ct][r] + bias, 0.f);
        }
        __syncthreads();

        // conv3 1x1: wave handles its 16 px, co-half coh
        bf16x8 blo = *(const bf16x8*)&sm.s4.As[pxg*16 + l15][q*8];
        bf16x8 bhi = *(const bf16x8*)&sm.s4.As[pxg*16 + l15][32 + q*8];
        f32x4 o3[2];
        #pragma unroll
        for (int mt = 0; mt < 2; ++mt) {
            const bf16* ap = W3 + (size_t)(coh*32 + mt*16 + l15)*64 + q*8;
            bf16x8 alo = *(const bf16x8*)ap;
            bf16x8 ahi = *(const bf16x8*)(ap + 32);
            f32x4 s = MFMA16(alo, blo, zero4());
            o3[mt] = MFMA16(ahi, bhi, s);
        }
        int pbase = y*128 + xq*32 + pxg*16 + l15;
        #pragma unroll
        for (int mt = 0; mt < 2; ++mt) {
            #pragma unroll
            for (int r = 0; r < 4; ++r) {
                int co = coh*32 + mt*16 + q*4 + r;
                size_t idx = (size_t)co*HW + pbase;
                out[idx] = x[idx] + c3b[co] + o3[mt][r];
            }
        }
    }
}

extern "C" void kernel_launch(void* const* d_in, const int* in_sizes, int n_in,
                              void* d_out, int out_size, void* d_ws, size_t ws_size,
                              hipStream_t stream) {
    (void)in_sizes; (void)n_in; (void)out_size; (void)ws_size;
    const float* x    = (const float*)d_in[0];
    const float* unet = (const float*)d_in[1];
    const float* wqk  = (const float*)d_in[2];
    const float* c1w  = (const float*)d_in[3];
    const float* c1b  = (const float*)d_in[4];
    const float* c2w  = (const float*)d_in[5];
    const float* c2b  = (const float*)d_in[6];
    const float* c3w  = (const float*)d_in[7];
    const float* c3b  = (const float*)d_in[8];
    const float* clw  = (const float*)d_in[9];
    const float* clb  = (const float*)d_in[10];
    float* out = (float*)d_out;

    char* ws = (char*)d_ws;
    bf16*  Q     = (bf16*)(ws + OFF_Q);
    bf16*  Qt    = (bf16*)(ws + OFF_QT);
    bf16*  Vt    = (bf16*)(ws + OFF_VT);
    float* Mf    = (float*)(ws + OFF_MF);
    bf16*  T     = (bf16*)(ws + OFF_T);
    bf16*  T2    = (bf16*)(ws + OFF_T2);
    bf16*  W1    = (bf16*)(ws + OFF_W1);
    bf16*  W2    = (bf16*)(ws + OFF_W2);
    bf16*  W3    = (bf16*)(ws + OFF_W3);
    bf16*  WLb   = (bf16*)(ws + OFF_WL);

    void* args[] = {
        (void*)&x, (void*)&unet, (void*)&wqk,
        (void*)&c1w, (void*)&c1b, (void*)&c2w, (void*)&c2b,
        (void*)&c3w, (void*)&c3b, (void*)&clw, (void*)&clb,
        (void*)&out,
        (void*)&Q, (void*)&Qt, (void*)&Vt, (void*)&Mf,
        (void*)&T, (void*)&T2, (void*)&W1, (void*)&W2, (void*)&W3, (void*)&WLb
    };
    hipLaunchCooperativeKernel((void*)k_fused, dim3(512), dim3(256), args, 0, stream);
}

// Round 2
// 173.182 us; speedup vs baseline: 2.1801x; 2.1801x over previous
//
#include <hip/hip_runtime.h>

typedef __bf16 bf16;
typedef bf16 bf16x8 __attribute__((ext_vector_type(8)));
typedef bf16 bf16x4 __attribute__((ext_vector_type(4)));
typedef float f32x4 __attribute__((ext_vector_type(4)));

#define MFMA16(a,b,c) __builtin_amdgcn_mfma_f32_16x16x32_bf16(a,b,c,0,0,0)

__device__ inline f32x4 zero4() { f32x4 z; z[0]=0.f; z[1]=0.f; z[2]=0.f; z[3]=0.f; return z; }

#define HW 16384   // 128*128
#define NQ 4096    // positions per window

// ---- workspace layout (bytes) ----
constexpr size_t OFF_Q    = 4096;                              // bf16 (4,4096,64)  2 MB  (row-major)
constexpr size_t OFF_QT   = OFF_Q  + (size_t)2097152;          // bf16 (4,64,4096)  2 MB  (Q^T)
constexpr size_t OFF_VT   = OFF_QT + (size_t)2097152;          // bf16 (4,64,4096)  2 MB
constexpr size_t OFF_MF   = OFF_VT + (size_t)2097152;          // fp32 (4,80,80) final M (atomic acc)
constexpr size_t OFF_T    = OFF_MF + (size_t)131072;           // bf16 HWC 2 MB
constexpr size_t OFF_T2   = OFF_T  + (size_t)2097152;          // bf16 HWC 2 MB
constexpr size_t OFF_W1   = OFF_T2 + (size_t)2097152;          // bf16 (9,64,64)
constexpr size_t OFF_W2   = OFF_W1 + 73728;
constexpr size_t OFF_W3   = OFF_W2 + 73728;                    // bf16 (64,64)
constexpr size_t OFF_WL   = OFF_W3 + 8192;                     // bf16 (64,64) convl weight

// ---------- K1: Q = normalize(x@wqk); writes Q, Q^T, V^T; zeroes Mf; bx>=512 weight prep ----------
__global__ __launch_bounds__(256) void k_qv(const float* __restrict__ x, const float* __restrict__ wqk,
                                            const float* __restrict__ w1, const float* __restrict__ w2,
                                            const float* __restrict__ w3, const float* __restrict__ wlc,
                                            bf16* __restrict__ Q, bf16* __restrict__ Qt,
                                            bf16* __restrict__ Vt, float* __restrict__ Mf,
                                            bf16* __restrict__ W1, bf16* __restrict__ W2,
                                            bf16* __restrict__ W3, bf16* __restrict__ WLb) {
    int t = threadIdx.x, bx = blockIdx.x;
    if (bx >= 512) {            // weight prep: 320 blocks
        int g = (bx - 512) * 256 + t;
        if (g < 36864) {
            int tap = g >> 12, co = (g >> 6) & 63, ci = g & 63;
            W1[g] = (bf16)w1[(co*64 + ci)*9 + tap];
        } else if (g < 73728) {
            int d = g - 36864;
            int tap = d >> 12, co = (d >> 6) & 63, ci = d & 63;
            W2[d] = (bf16)w2[(co*64 + ci)*9 + tap];
        } else if (g < 77824) {
            int d = g - 73728;
            W3[d] = (bf16)w3[d];
        } else if (g < 81920) {
            int d = g - 77824;
            WLb[d] = (bf16)wlc[(d >> 6)*65 + (d & 63)];
        }
        return;
    }
    int y = bx >> 2, x0 = (bx & 3) * 32;
    __shared__ float xs[32][65];
    __shared__ float wl[4096];
    __shared__ bf16 qts[64][34];   // [e][pixel-in-block]

    if (bx < 25) {     // zero the atomic M accumulator (25600 floats)
        int i = bx*1024 + t*4;
        if (i < 25600) {
            float4 z; z.x = 0.f; z.y = 0.f; z.z = 0.f; z.w = 0.f;
            *(float4*)(Mf + i) = z;
        }
    }

    // load 32 pixels x 64 channels; write Vt on the way (vectorized even/odd stores)
    {
        int c = t >> 2, seg = t & 3;
        const float4* xp = (const float4*)(x + (size_t)c*HW + y*128 + x0 + seg*8);
        float f[8];
        float4 v0 = xp[0], v1 = xp[1];
        f[0]=v0.x; f[1]=v0.y; f[2]=v0.z; f[3]=v0.w;
        f[4]=v1.x; f[5]=v1.y; f[6]=v1.z; f[7]=v1.w;
        #pragma unroll
        for (int k = 0; k < 8; ++k) xs[seg*8 + k][c] = f[k];
        int dh = y & 1;
        int base_n = (y >> 1)*64 + ((x0 + seg*8) >> 1);
        bf16x4 ve, vo;
        #pragma unroll
        for (int j = 0; j < 4; ++j) { ve[j] = (bf16)f[2*j]; vo[j] = (bf16)f[2*j+1]; }
        *(bf16x4*)(Vt + ((size_t)((dh*2 + 0)*64 + c))*NQ + base_n) = ve;
        *(bf16x4*)(Vt + ((size_t)((dh*2 + 1)*64 + c))*NQ + base_n) = vo;
    }
    // load wqk (64x64 fp32)
    {
        const float4* wp = (const float4*)wqk;
        #pragma unroll
        for (int k = 0; k < 4; ++k) {
            float4 v = wp[t*4 + k];
            wl[t*16 + k*4 + 0] = v.x; wl[t*16 + k*4 + 1] = v.y;
            wl[t*16 + k*4 + 2] = v.z; wl[t*16 + k*4 + 3] = v.w;
        }
    }
    __syncthreads();

    int p = t >> 3, eg = t & 7;
    float acc[8];
    #pragma unroll
    for (int k = 0; k < 8; ++k) acc[k] = 0.f;
    for (int c = 0; c < 64; ++c) {
        float xv = xs[p][c];
        const float* wr = &wl[c*64 + eg*8];
        #pragma unroll
        for (int k = 0; k < 8; ++k) acc[k] += xv * wr[k];
    }
    float ss = 0.f;
    #pragma unroll
    for (int k = 0; k < 8; ++k) ss += acc[k]*acc[k];
    ss += __shfl_xor(ss, 1);
    ss += __shfl_xor(ss, 2);
    ss += __shfl_xor(ss, 4);
    float inv = 1.f / (sqrtf(ss) + 1e-8f);

    int xp2 = x0 + p;
    int b2 = (y & 1)*2 + (xp2 & 1);
    int nidx = (y >> 1)*64 + (xp2 >> 1);
    bf16x8 qv;
    #pragma unroll
    for (int k = 0; k < 8; ++k) qv[k] = (bf16)(acc[k]*inv);
    *(bf16x8*)(Q + ((size_t)b2*NQ + nidx)*64 + eg*8) = qv;
    #pragma unroll
    for (int k = 0; k < 8; ++k) qts[eg*8 + k][p] = qv[k];
    __syncthreads();

    // transpose write: Q^T[b2][e][n]
    {
        int e = t >> 2, par = (t >> 1) & 1, seg2 = t & 1;
        int b2w = (y & 1)*2 + par;
        int nbase = (y >> 1)*64 + (x0 >> 1) + seg2*8;
        bf16x8 qt;
        #pragma unroll
        for (int j = 0; j < 8; ++j) qt[j] = qts[e][par + 2*(seg2*8 + j)];
        *(bf16x8*)(Qt + ((size_t)b2w*64 + e)*NQ + nbase) = qt;
    }
}

// ---------- K2: M = [V|1]^T [Qhat|1]  (80x80, K 16-split, atomicAdd into Mf), 64 blocks ----------
__global__ __launch_bounds__(256) void k_gemm1(const bf16* __restrict__ Vt, const bf16* __restrict__ Qt,
                                               float* __restrict__ Mf) {
    int bx = blockIdx.x;               // 64 = kc*4 + b2
    int b2 = bx & 3, kc = bx >> 2;     // kc 0..15
    int tid = threadIdx.x, w = tid >> 6, lane = tid & 63, q = lane >> 4, l15 = lane & 15;
    const bf16* Vb  = Vt + (size_t)b2*64*NQ;
    const bf16* Qtb = Qt + (size_t)b2*64*NQ;
    bf16x8 onesfrag = {};
    if (l15 == 0) {
        #pragma unroll
        for (int k = 0; k < 8; ++k) onesfrag[k] = (bf16)1.0f;
    }
    f32x4 acc[5], acc1[5];
    #pragma unroll
    for (int nt = 0; nt < 5; ++nt) { acc[nt] = zero4(); acc1[nt] = zero4(); }

    int k0 = kc*256 + q*8;
    for (int it = 0; it < 8; ++it) {
        int kk = k0 + it*32;
        bf16x8 av = *(const bf16x8*)(Vb + (size_t)(w*16 + l15)*NQ + kk);
        bf16x8 b[5];
        #pragma unroll
        for (int nt = 0; nt < 4; ++nt) b[nt] = *(const bf16x8*)(Qtb + (size_t)(nt*16 + l15)*NQ + kk);
        b[4] = onesfrag;                               // col 64 = ones (c0 / m1)
        #pragma unroll
        for (int nt = 0; nt < 5; ++nt) {
            acc[nt] = MFMA16(av, b[nt], acc[nt]);
            if (w == 0) acc1[nt] = MFMA16(onesfrag, b[nt], acc1[nt]);  // row 64 = colsums
        }
    }
    float* mp = Mf + (size_t)b2*6400;
    #pragma unroll
    for (int nt = 0; nt < 5; ++nt)
        #pragma unroll
        for (int r = 0; r < 4; ++r)
            if (nt < 4 || l15 == 0)
                unsafeAtomicAdd(&mp[(w*16 + q*4 + r)*80 + nt*16 + l15], acc[nt][r]);
    if (w == 0 && q == 0) {
        #pragma unroll
        for (int nt = 0; nt < 5; ++nt)
            if (nt < 4 || l15 == 0)
                unsafeAtomicAdd(&mp[64*80 + nt*16 + l15], acc1[nt][0]);
    }
}

// ---------- K3: fused gemm2 (attn tile) + convl (65->64 1x1) + x -> T (HWC bf16) ----------
__global__ __launch_bounds__(256) void k_g2convl(const bf16* __restrict__ Q, const float* __restrict__ Mf,
                                                 const float* __restrict__ unet, const float* __restrict__ x,
                                                 const bf16* __restrict__ WLb, const float* __restrict__ wl,
                                                 const float* __restrict__ bl, bf16* __restrict__ T) {
    int t = threadIdx.x, bx = blockIdx.x;   // bx = pixel-block = (n & 255)
    int p0 = bx * 64;
    __shared__ __align__(16) bf16 Msl[4][80][88];
    __shared__ __align__(16) bf16 As[64][72];   // [px(=value ch)][ci(=attn ch)]

    #pragma unroll
    for (int ii = 0; ii < 25; ++ii) {
        int i = ii*1024 + t*4;
        float4 v = *(const float4*)(Mf + i);
        int b2i = i / 6400, rem = i - b2i*6400;
        int rr = rem / 80, cc = rem - rr*80;
        bf16x4 pk; pk[0] = (bf16)v.x; pk[1] = (bf16)v.y; pk[2] = (bf16)v.z; pk[3] = (bf16)v.w;
        *(bf16x4*)&Msl[b2i][rr][cc] = pk;
    }
    __syncthreads();

    int w = t >> 6, lane = t & 63, q = lane >> 4, l15 = lane & 15;
    {   // stage 1: attn tile. wave w = window b2; A rows n = m*256 + bx (m = l15)
        int b2 = w;
        const bf16* qp = Q + ((size_t)b2*NQ + l15*256 + bx)*64 + q*8;
        bf16x8 a0 = *(const bf16x8*)qp;
        bf16x8 a1 = *(const bf16x8*)(qp + 32);
        f32x4 acc[5];
        #pragma unroll
        for (int ct = 0; ct < 5; ++ct) {
            bf16x8 bf0 = *(const bf16x8*)&Msl[b2][ct*16 + l15][q*8];
            bf16x8 bf1 = *(const bf16x8*)&Msl[b2][ct*16 + l15][32 + q*8];
            f32x4 s = MFMA16(a0, bf0, zero4());
            acc[ct] = MFMA16(a1, bf1, s);
        }
        float c0v[4];
        #pragma unroll
        for (int ct = 0; ct < 4; ++ct) c0v[ct] = (float)Msl[b2][ct*16 + l15][64];
        #pragma unroll
        for (int r = 0; r < 4; ++r) {
            float ldot = __shfl(acc[4][r], lane & 48);
            float rl = 1.0f / fmaf(ldot, 0.125f, 4096.0f);
            #pragma unroll
            for (int ct = 0; ct < 4; ++ct)
                As[ct*16 + l15][b2*16 + q*4 + r] = (bf16)(fmaf(acc[ct][r], 0.125f, c0v[ct]) * rl);
        }
    }
    __syncthreads();

    // stage 2: convl — wave w = px-block (n = w*16+l15); A = WLb rows (m = co) -> co in regs,
    // contiguous bf16x4 stores to T
    int px = w*16 + l15;
    bf16x8 b0 = *(const bf16x8*)&As[px][q*8];
    bf16x8 b1 = *(const bf16x8*)&As[px][32 + q*8];
    float u = unet[p0 + px];
    #pragma unroll
    for (int mt = 0; mt < 4; ++mt) {
        const bf16* ap = WLb + (size_t)(mt*16 + l15)*64 + q*8;
        bf16x8 a0 = *(const bf16x8*)ap;
        bf16x8 a1 = *(const bf16x8*)(ap + 32);
        f32x4 s = MFMA16(a0, b0, zero4());
        f32x4 o = MFMA16(a1, b1, s);
        bf16x4 st;
        #pragma unroll
        for (int r = 0; r < 4; ++r) {
            int co = mt*16 + q*4 + r;
            float v = o[r] + u*wl[co*65 + 64] + bl[co] + x[(size_t)co*HW + p0 + px];
            st[r] = (bf16)v;
        }
        *(bf16x4*)(T + (size_t)(p0 + px)*64 + mt*16 + q*4) = st;
    }
}

// ---------- K4: conv1 3x3 dil1 + bias + relu, HWC bf16 -> HWC bf16, co 2-way, LDS weights ----------
__global__ __launch_bounds__(256, 2) void k_conv3x3(const bf16* __restrict__ IN, const bf16* __restrict__ WT,
                                                    const float* __restrict__ B, bf16* __restrict__ OUT,
                                                    int dil) {
    int tid = threadIdx.x, bx = blockIdx.x;
    int y = bx >> 2, xh = (bx >> 1) & 1, coh = bx & 1;
    int w = tid >> 6, lane = tid & 63, q = lane >> 4, l15 = lane & 15;
    int xb = xh*64 + w*16;

    __shared__ __align__(16) bf16 wsl[9][32][72];
    for (int i = tid; i < 2304; i += 256) {
        int tap = i >> 8, rem = i & 255, co = rem >> 3, k8 = (rem & 7) * 8;
        *(bf16x8*)&wsl[tap][co][k8] =
            *(const bf16x8*)(WT + (((size_t)(tap*64 + coh*32 + co)) << 6) + k8);
    }
    __syncthreads();

    f32x4 o[2];
    o[0] = zero4(); o[1] = zero4();
    #pragma unroll
    for (int ky = 0; ky < 3; ++ky) {
        int yy = y + (ky - 1)*dil;
        bool yok = (yy >= 0) && (yy < 128);
        #pragma unroll
        for (int kx = 0; kx < 3; ++kx) {
            int xx = xb + l15 + (kx - 1)*dil;
            bool ok = yok && (xx >= 0) && (xx < 128);
            bf16x8 alo = {}, ahi = {};
            if (ok) {
                const bf16* ip = IN + (size_t)(yy*128 + xx)*64 + q*8;
                alo = *(const bf16x8*)ip;
                ahi = *(const bf16x8*)(ip + 32);
            }
            int tap = ky*3 + kx;
            #pragma unroll
            for (int ct = 0; ct < 2; ++ct) {
                bf16x8 blo = *(const bf16x8*)&wsl[tap][ct*16 + l15][q*8];
                bf16x8 bhi = *(const bf16x8*)&wsl[tap][ct*16 + l15][32 + q*8];
                o[ct] = MFMA16(alo, blo, o[ct]);
                o[ct] = MFMA16(ahi, bhi, o[ct]);
            }
        }
    }
    #pragma unroll
    for (int ct = 0; ct < 2; ++ct) {
        int co = coh*32 + ct*16 + l15;
        float bias = B[co];
        #pragma unroll
        for (int r = 0; r < 4; ++r) {
            float v = fmaxf(o[ct][r] + bias, 0.f);
            OUT[(size_t)(y*128 + xb + q*4 + r)*64 + co] = (bf16)v;
        }
    }
}

// ---------- K5: fused conv2 (3x3 dil2, relu) + conv3 (1x1) + x -> out (CHW fp32) ----------
__global__ __launch_bounds__(256) void k_conv23(const bf16* __restrict__ IN, const bf16* __restrict__ W2T,
                                                const float* __restrict__ b2v, const bf16* __restrict__ W3,
                                                const float* __restrict__ b3, const float* __restrict__ x,
                                                float* __restrict__ out) {
    int tid = threadIdx.x, bx = blockIdx.x;
    int y = bx >> 2, xq = bx & 3;
    int w = tid >> 6, lane = tid & 63, q = lane >> 4, l15 = lane & 15;
    int pxg = w & 1, coh = w >> 1;
    int xb = xq*32 + pxg*16;

    __shared__ __align__(16) bf16 As[32][72];   // [px-in-block][co]

    f32x4 o[2];
    o[0] = zero4(); o[1] = zero4();
    #pragma unroll
    for (int ky = 0; ky < 3; ++ky) {
        int yy = y + (ky - 1)*2;
        bool yok = (yy >= 0) && (yy < 128);
        #pragma unroll
        for (int kx = 0; kx < 3; ++kx) {
            int xx = xb + l15 + (kx - 1)*2;
            bool ok = yok && (xx >= 0) && (xx < 128);
            bf16x8 alo = {}, ahi = {};
            if (ok) {
                const bf16* ip = IN + (size_t)(yy*128 + xx)*64 + q*8;
                alo = *(const bf16x8*)ip;
                ahi = *(const bf16x8*)(ip + 32);
            }
            int tap = ky*3 + kx;
            #pragma unroll
            for (int ct = 0; ct < 2; ++ct) {
                const bf16* wp = W2T + (size_t)(tap*64 + coh*32 + ct*16 + l15)*64 + q*8;
                bf16x8 blo = *(const bf16x8*)wp;
                bf16x8 bhi = *(const bf16x8*)(wp + 32);
                o[ct] = MFMA16(alo, blo, o[ct]);
                o[ct] = MFMA16(ahi, bhi, o[ct]);
            }
        }
    }
    #pragma unroll
    for (int ct = 0; ct < 2; ++ct) {
        int co = coh*32 + ct*16 + l15;
        float bias = b2v[co];
        #pragma unroll
        for (int r = 0; r < 4; ++r)
            As[pxg*16 + q*4 + r][co] = (bf16)fmaxf(o[ct][r] + bias, 0.f);
    }
    __syncthreads();

    // conv3 1x1: wave handles its 16 px, co-half coh
    bf16x8 blo = *(const bf16x8*)&As[pxg*16 + l15][q*8];
    bf16x8 bhi = *(const bf16x8*)&As[pxg*16 + l15][32 + q*8];
    f32x4 o3[2];
    #pragma unroll
    for (int mt = 0; mt < 2; ++mt) {
        const bf16* ap = W3 + (size_t)(coh*32 + mt*16 + l15)*64 + q*8;
        bf16x8 alo = *(const bf16x8*)ap;
        bf16x8 ahi = *(const bf16x8*)(ap + 32);
        f32x4 s = MFMA16(alo, blo, zero4());
        o3[mt] = MFMA16(ahi, bhi, s);
    }
    int pbase = y*128 + xq*32 + pxg*16 + l15;
    #pragma unroll
    for (int mt = 0; mt < 2; ++mt) {
        #pragma unroll
        for (int r = 0; r < 4; ++r) {
            int co = coh*32 + mt*16 + q*4 + r;
            size_t idx = (size_t)co*HW + pbase;
            out[idx] = x[idx] + b3[co] + o3[mt][r];
        }
    }
}

extern "C" void kernel_launch(void* const* d_in, const int* in_sizes, int n_in,
                              void* d_out, int out_size, void* d_ws, size_t ws_size,
                              hipStream_t stream) {
    (void)in_sizes; (void)n_in; (void)out_size; (void)ws_size;
    const float* x    = (const float*)d_in[0];
    const float* unet = (const float*)d_in[1];
    const float* wqk  = (const float*)d_in[2];
    const float* c1w  = (const float*)d_in[3];
    const float* c1b  = (const float*)d_in[4];
    const float* c2w  = (const float*)d_in[5];
    const float* c2b  = (const float*)d_in[6];
    const float* c3w  = (const float*)d_in[7];
    const float* c3b  = (const float*)d_in[8];
    const float* clw  = (const float*)d_in[9];
    const float* clb  = (const float*)d_in[10];
    float* out = (float*)d_out;

    char* ws = (char*)d_ws;
    bf16*  Q     = (bf16*)(ws + OFF_Q);
    bf16*  Qt    = (bf16*)(ws + OFF_QT);
    bf16*  Vt    = (bf16*)(ws + OFF_VT);
    float* Mf    = (float*)(ws + OFF_MF);
    bf16*  T     = (bf16*)(ws + OFF_T);
    bf16*  T2    = (bf16*)(ws + OFF_T2);
    bf16*  W1    = (bf16*)(ws + OFF_W1);
    bf16*  W2    = (bf16*)(ws + OFF_W2);
    bf16*  W3    = (bf16*)(ws + OFF_W3);
    bf16*  WLb   = (bf16*)(ws + OFF_WL);

    // MEASUREMENT ROUND: run the full (idempotent) pipeline TWICE.
    // dur_us - 122 gives the true kernel-time sum S, discriminating
    // "harness-floor-dominated" (model A) from "kernel-body-dominated" (model B).
    for (int rep = 0; rep < 2; ++rep) {
        k_qv<<<dim3(832),    dim3(256), 0, stream>>>(x, wqk, c1w, c2w, c3w, clw, Q, Qt, Vt, Mf,
                                                     W1, W2, W3, WLb);
        k_gemm1<<<dim3(64),  dim3(256), 0, stream>>>(Vt, Qt, Mf);
        k_g2convl<<<dim3(256), dim3(256), 0, stream>>>(Q, Mf, unet, x, WLb, clw, clb, T);
        k_conv3x3<<<dim3(512), dim3(256), 0, stream>>>(T, W1, c1b, T2, 1);
        k_conv23<<<dim3(512), dim3(256), 0, stream>>>(T2, W2, c2b, W3, c3b, x, out);
    }
}

// Round 3
// 158.185 us; speedup vs baseline: 2.3868x; 1.0948x over previous
//
#include <hip/hip_runtime.h>

typedef __bf16 bf16;
typedef bf16 bf16x8 __attribute__((ext_vector_type(8)));
typedef bf16 bf16x4 __attribute__((ext_vector_type(4)));
typedef float f32x4 __attribute__((ext_vector_type(4)));

#define MFMA16(a,b,c) __builtin_amdgcn_mfma_f32_16x16x32_bf16(a,b,c,0,0,0)

__device__ inline f32x4 zero4() { f32x4 z; z[0]=0.f; z[1]=0.f; z[2]=0.f; z[3]=0.f; return z; }

#define HW 16384   // 128*128
#define NQ 4096    // positions per window

// M accumulator lives OUTSIDE the (re-poisoned) workspace: module-scope device
// memory is zero-initialized at load, and k_conv23 (the last kernel of every
// chain) re-zeroes it for the next replay. Invariant: MBANK == 0 when k_qv runs.
__device__ __align__(16) float MBANK[25600];   // fp32 (4 windows, 80, 80)

// ---- workspace layout (bytes) ----
constexpr size_t OFF_Q    = 4096;                              // bf16 (4,4096,64)  2 MB  (row-major)
constexpr size_t OFF_T    = OFF_Q  + (size_t)2097152;          // bf16 HWC 2 MB
constexpr size_t OFF_T2   = OFF_T  + (size_t)2097152;          // bf16 HWC 2 MB
constexpr size_t OFF_W1   = OFF_T2 + (size_t)2097152;          // bf16 (9,64,64)
constexpr size_t OFF_W2   = OFF_W1 + 73728;
constexpr size_t OFF_W3   = OFF_W2 + 73728;                    // bf16 (64,64)
constexpr size_t OFF_WL   = OFF_W3 + 8192;                     // bf16 (64,64) convl weight

// ---------- K1: Q = normalize(x@wqk); writes Q; accumulates M into MBANK via MFMA+atomics;
// ----------     bx>=512 weight prep ----------
__global__ __launch_bounds__(256) void k_qv(const float* __restrict__ x, const float* __restrict__ wqk,
                                            const float* __restrict__ w1, const float* __restrict__ w2,
                                            const float* __restrict__ w3, const float* __restrict__ wlc,
                                            bf16* __restrict__ Q,
                                            bf16* __restrict__ W1, bf16* __restrict__ W2,
                                            bf16* __restrict__ W3, bf16* __restrict__ WLb) {
    int t = threadIdx.x, bx = blockIdx.x;
    if (bx >= 512) {            // weight prep: 320 blocks
        int g = (bx - 512) * 256 + t;
        if (g < 36864) {
            int tap = g >> 12, co = (g >> 6) & 63, ci = g & 63;
            W1[g] = (bf16)w1[(co*64 + ci)*9 + tap];
        } else if (g < 73728) {
            int d = g - 36864;
            int tap = d >> 12, co = (d >> 6) & 63, ci = d & 63;
            W2[d] = (bf16)w2[(co*64 + ci)*9 + tap];
        } else if (g < 77824) {
            int d = g - 73728;
            W3[d] = (bf16)w3[d];
        } else if (g < 81920) {
            int d = g - 77824;
            WLb[d] = (bf16)wlc[(d >> 6)*65 + (d & 63)];
        }
        return;
    }
    int y = bx >> 2, x0 = (bx & 3) * 32;
    __shared__ float xs[32][65];
    __shared__ float wl[4096];
    __shared__ bf16 qts[64][34];   // [e][pixel-in-block]

    // load 32 pixels x 64 channels into LDS
    {
        int c = t >> 2, seg = t & 3;
        const float4* xp = (const float4*)(x + (size_t)c*HW + y*128 + x0 + seg*8);
        float f[8];
        float4 v0 = xp[0], v1 = xp[1];
        f[0]=v0.x; f[1]=v0.y; f[2]=v0.z; f[3]=v0.w;
        f[4]=v1.x; f[5]=v1.y; f[6]=v1.z; f[7]=v1.w;
        #pragma unroll
        for (int k = 0; k < 8; ++k) xs[seg*8 + k][c] = f[k];
    }
    // load wqk (64x64 fp32)
    {
        const float4* wp = (const float4*)wqk;
        #pragma unroll
        for (int k = 0; k < 4; ++k) {
            float4 v = wp[t*4 + k];
            wl[t*16 + k*4 + 0] = v.x; wl[t*16 + k*4 + 1] = v.y;
            wl[t*16 + k*4 + 2] = v.z; wl[t*16 + k*4 + 3] = v.w;
        }
    }
    __syncthreads();

    int p = t >> 3, eg = t & 7;
    float acc[8];
    #pragma unroll
    for (int k = 0; k < 8; ++k) acc[k] = 0.f;
    for (int c = 0; c < 64; ++c) {
        float xv = xs[p][c];
        const float* wr = &wl[c*64 + eg*8];
        #pragma unroll
        for (int k = 0; k < 8; ++k) acc[k] += xv * wr[k];
    }
    float ss = 0.f;
    #pragma unroll
    for (int k = 0; k < 8; ++k) ss += acc[k]*acc[k];
    ss += __shfl_xor(ss, 1);
    ss += __shfl_xor(ss, 2);
    ss += __shfl_xor(ss, 4);
    float inv = 1.f / (sqrtf(ss) + 1e-8f);

    int xp2 = x0 + p;
    int b2 = (y & 1)*2 + (xp2 & 1);
    int nidx = (y >> 1)*64 + (xp2 >> 1);
    bf16x8 qv;
    #pragma unroll
    for (int k = 0; k < 8; ++k) qv[k] = (bf16)(acc[k]*inv);
    *(bf16x8*)(Q + ((size_t)b2*NQ + nidx)*64 + eg*8) = qv;
    #pragma unroll
    for (int k = 0; k < 8; ++k) qts[eg*8 + k][p] = qv[k];
    __syncthreads();

    // ---- M-accumulation: this block's 80x80 contribution for its two windows ----
    // M[v][q] = sum_n V[v][n]*Qhat[q][n]; block holds 16 pixels of window (dh,0)
    // (even x-parity) and 16 of (dh,1) (odd). MFMA A = V rows (parity-masked over k),
    // B = Qhat rows from qts. D rows = v_ch, cols = q_ch. Wave w4 owns v-ch tile w4.
    {
        int w4 = t >> 6, lane = t & 63, l15 = lane & 15, g = lane >> 4;
        int dh = y & 1;

        bf16x8 bv0, bv1, bv2, bv3, bown;
        #pragma unroll
        for (int j = 0; j < 8; ++j) {
            int px = g*8 + j;
            bv0[j] = qts[ 0 + l15][px];
            bv1[j] = qts[16 + l15][px];
            bv2[j] = qts[32 + l15][px];
            bv3[j] = qts[48 + l15][px];
            bown[j] = qts[w4*16 + l15][px];     // == bv[w4], LDS-indexed to stay in regs
        }
        bf16x8 ave = {}, avo = {};
        #pragma unroll
        for (int j = 0; j < 8; ++j) {
            bf16 v = (bf16)xs[g*8 + j][w4*16 + l15];
            if (j & 1) avo[j] = v; else ave[j] = v;
        }
        bf16x8 onesE = {}, onesO = {}, onesA;
        #pragma unroll
        for (int j = 0; j < 8; ++j) {
            if (j & 1) onesO[j] = (bf16)1.0f; else onesE[j] = (bf16)1.0f;
            onesA[j] = (bf16)1.0f;
        }

        f32x4 accm[8];                 // [par*4 + nt]
        #pragma unroll
        for (int i = 0; i < 8; ++i) accm[i] = zero4();
        accm[0] = MFMA16(ave, bv0, accm[0]);
        accm[1] = MFMA16(ave, bv1, accm[1]);
        accm[2] = MFMA16(ave, bv2, accm[2]);
        accm[3] = MFMA16(ave, bv3, accm[3]);
        accm[4] = MFMA16(avo, bv0, accm[4]);
        accm[5] = MFMA16(avo, bv1, accm[5]);
        accm[6] = MFMA16(avo, bv2, accm[6]);
        accm[7] = MFMA16(avo, bv3, accm[7]);
        f32x4 accC0 = MFMA16(ave, onesA, zero4());   // ones-col: V rowsums (col 64)
        f32x4 accC1 = MFMA16(avo, onesA, zero4());
        f32x4 accR0 = MFMA16(onesE, bown, zero4());  // ones-row: Qhat colsums (row 64), nt=w4
        f32x4 accR1 = MFMA16(onesO, bown, zero4());

        float* mp0 = MBANK + (size_t)(dh*2 + 0)*6400;
        float* mp1 = MBANK + (size_t)(dh*2 + 1)*6400;
        #pragma unroll
        for (int nt = 0; nt < 4; ++nt)
            #pragma unroll
            for (int r = 0; r < 4; ++r) {
                int idx = (w4*16 + g*4 + r)*80 + nt*16 + l15;
                unsafeAtomicAdd(&mp0[idx], accm[nt][r]);
                unsafeAtomicAdd(&mp1[idx], accm[4 + nt][r]);
            }
        if (l15 == 0) {
            #pragma unroll
            for (int r = 0; r < 4; ++r) {
                int row = w4*16 + g*4 + r;
                unsafeAtomicAdd(&mp0[row*80 + 64], accC0[r]);
                unsafeAtomicAdd(&mp1[row*80 + 64], accC1[r]);
            }
        }
        if (g == 0) {   // D rows all equal for ones-A; take r=0
            unsafeAtomicAdd(&mp0[64*80 + w4*16 + l15], accR0[0]);
            unsafeAtomicAdd(&mp1[64*80 + w4*16 + l15], accR1[0]);
        }
    }
}

// ---------- K3: fused gemm2 (attn tile) + convl (65->64 1x1) + x -> T (HWC bf16) ----------
__global__ __launch_bounds__(256) void k_g2convl(const bf16* __restrict__ Q,
                                                 const float* __restrict__ unet, const float* __restrict__ x,
                                                 const bf16* __restrict__ WLb, const float* __restrict__ wl,
                                                 const float* __restrict__ bl, bf16* __restrict__ T) {
    int t = threadIdx.x, bx = blockIdx.x;   // bx = pixel-block = (n & 255)
    int p0 = bx * 64;
    __shared__ __align__(16) bf16 Msl[4][80][88];
    __shared__ __align__(16) bf16 As[64][72];   // [px(=value ch)][ci(=attn ch)]

    #pragma unroll
    for (int ii = 0; ii < 25; ++ii) {
        int i = ii*1024 + t*4;
        float4 v = *(const float4*)(MBANK + i);
        int b2i = i / 6400, rem = i - b2i*6400;
        int rr = rem / 80, cc = rem - rr*80;
        bf16x4 pk; pk[0] = (bf16)v.x; pk[1] = (bf16)v.y; pk[2] = (bf16)v.z; pk[3] = (bf16)v.w;
        *(bf16x4*)&Msl[b2i][rr][cc] = pk;
    }
    __syncthreads();

    int w = t >> 6, lane = t & 63, q = lane >> 4, l15 = lane & 15;
    {   // stage 1: attn tile. wave w = window b2; A rows n = m*256 + bx (m = l15)
        int b2 = w;
        const bf16* qp = Q + ((size_t)b2*NQ + l15*256 + bx)*64 + q*8;
        bf16x8 a0 = *(const bf16x8*)qp;
        bf16x8 a1 = *(const bf16x8*)(qp + 32);
        f32x4 acc[5];
        #pragma unroll
        for (int ct = 0; ct < 5; ++ct) {
            bf16x8 bf0 = *(const bf16x8*)&Msl[b2][ct*16 + l15][q*8];
            bf16x8 bf1 = *(const bf16x8*)&Msl[b2][ct*16 + l15][32 + q*8];
            f32x4 s = MFMA16(a0, bf0, zero4());
            acc[ct] = MFMA16(a1, bf1, s);
        }
        float c0v[4];
        #pragma unroll
        for (int ct = 0; ct < 4; ++ct) c0v[ct] = (float)Msl[b2][ct*16 + l15][64];
        #pragma unroll
        for (int r = 0; r < 4; ++r) {
            float ldot = __shfl(acc[4][r], lane & 48);
            float rl = 1.0f / fmaf(ldot, 0.125f, 4096.0f);
            #pragma unroll
            for (int ct = 0; ct < 4; ++ct)
                As[ct*16 + l15][b2*16 + q*4 + r] = (bf16)(fmaf(acc[ct][r], 0.125f, c0v[ct]) * rl);
        }
    }
    __syncthreads();

    // stage 2: convl — wave w = px-block (n = w*16+l15); A = WLb rows (m = co) -> co in regs,
    // contiguous bf16x4 stores to T
    int px = w*16 + l15;
    bf16x8 b0 = *(const bf16x8*)&As[px][q*8];
    bf16x8 b1 = *(const bf16x8*)&As[px][32 + q*8];
    float u = unet[p0 + px];
    #pragma unroll
    for (int mt = 0; mt < 4; ++mt) {
        const bf16* ap = WLb + (size_t)(mt*16 + l15)*64 + q*8;
        bf16x8 a0 = *(const bf16x8*)ap;
        bf16x8 a1 = *(const bf16x8*)(ap + 32);
        f32x4 s = MFMA16(a0, b0, zero4());
        f32x4 o = MFMA16(a1, b1, s);
        bf16x4 st;
        #pragma unroll
        for (int r = 0; r < 4; ++r) {
            int co = mt*16 + q*4 + r;
            float v = o[r] + u*wl[co*65 + 64] + bl[co] + x[(size_t)co*HW + p0 + px];
            st[r] = (bf16)v;
        }
        *(bf16x4*)(T + (size_t)(p0 + px)*64 + mt*16 + q*4) = st;
    }
}

// ---------- K4: conv1 3x3 dil1 + bias + relu, HWC bf16 -> HWC bf16, co 2-way, LDS weights ----------
__global__ __launch_bounds__(256, 2) void k_conv3x3(const bf16* __restrict__ IN, const bf16* __restrict__ WT,
                                                    const float* __restrict__ B, bf16* __restrict__ OUT,
                                                    int dil) {
    int tid = threadIdx.x, bx = blockIdx.x;
    int y = bx >> 2, xh = (bx >> 1) & 1, coh = bx & 1;
    int w = tid >> 6, lane = tid & 63, q = lane >> 4, l15 = lane & 15;
    int xb = xh*64 + w*16;

    __shared__ __align__(16) bf16 wsl[9][32][72];
    for (int i = tid; i < 2304; i += 256) {
        int tap = i >> 8, rem = i & 255, co = rem >> 3, k8 = (rem & 7) * 8;
        *(bf16x8*)&wsl[tap][co][k8] =
            *(const bf16x8*)(WT + (((size_t)(tap*64 + coh*32 + co)) << 6) + k8);
    }
    __syncthreads();

    f32x4 o[2];
    o[0] = zero4(); o[1] = zero4();
    #pragma unroll
    for (int ky = 0; ky < 3; ++ky) {
        int yy = y + (ky - 1)*dil;
        bool yok = (yy >= 0) && (yy < 128);
        #pragma unroll
        for (int kx = 0; kx < 3; ++kx) {
            int xx = xb + l15 + (kx - 1)*dil;
            bool ok = yok && (xx >= 0) && (xx < 128);
            bf16x8 alo = {}, ahi = {};
            if (ok) {
                const bf16* ip = IN + (size_t)(yy*128 + xx)*64 + q*8;
                alo = *(const bf16x8*)ip;
                ahi = *(const bf16x8*)(ip + 32);
            }
            int tap = ky*3 + kx;
            #pragma unroll
            for (int ct = 0; ct < 2; ++ct) {
                bf16x8 blo = *(const bf16x8*)&wsl[tap][ct*16 + l15][q*8];
                bf16x8 bhi = *(const bf16x8*)&wsl[tap][ct*16 + l15][32 + q*8];
                o[ct] = MFMA16(alo, blo, o[ct]);
                o[ct] = MFMA16(ahi, bhi, o[ct]);
            }
        }
    }
    #pragma unroll
    for (int ct = 0; ct < 2; ++ct) {
        int co = coh*32 + ct*16 + l15;
        float bias = B[co];
        #pragma unroll
        for (int r = 0; r < 4; ++r) {
            float v = fmaxf(o[ct][r] + bias, 0.f);
            OUT[(size_t)(y*128 + xb + q*4 + r)*64 + co] = (bf16)v;
        }
    }
}

// ---------- K5: fused conv2 (3x3 dil2, relu) + conv3 (1x1) + x -> out (CHW fp32);
// ----------     also re-zeroes MBANK for the next replay ----------
__global__ __launch_bounds__(256) void k_conv23(const bf16* __restrict__ IN, const bf16* __restrict__ W2T,
                                                const float* __restrict__ b2v, const bf16* __restrict__ W3,
                                                const float* __restrict__ b3, const float* __restrict__ x,
                                                float* __restrict__ out) {
    int tid = threadIdx.x, bx = blockIdx.x;

    // MBANK was fully consumed by k_g2convl (two dispatches ago); reset it so the
    // next graph replay's k_qv starts from zero. 512 blocks x 50 floats = 25600.
    if (tid < 50) MBANK[bx*50 + tid] = 0.f;

    int y = bx >> 2, xq = bx & 3;
    int w = tid >> 6, lane = tid & 63, q = lane >> 4, l15 = lane & 15;
    int pxg = w & 1, coh = w >> 1;
    int xb = xq*32 + pxg*16;

    __shared__ __align__(16) bf16 As[32][72];   // [px-in-block][co]

    f32x4 o[2];
    o[0] = zero4(); o[1] = zero4();
    #pragma unroll
    for (int ky = 0; ky < 3; ++ky) {
        int yy = y + (ky - 1)*2;
        bool yok = (yy >= 0) && (yy < 128);
        #pragma unroll
        for (int kx = 0; kx < 3; ++kx) {
            int xx = xb + l15 + (kx - 1)*2;
            bool ok = yok && (xx >= 0) && (xx < 128);
            bf16x8 alo = {}, ahi = {};
            if (ok) {
                const bf16* ip = IN + (size_t)(yy*128 + xx)*64 + q*8;
                alo = *(const bf16x8*)ip;
                ahi = *(const bf16x8*)(ip + 32);
            }
            int tap = ky*3 + kx;
            #pragma unroll
            for (int ct = 0; ct < 2; ++ct) {
                const bf16* wp = W2T + (size_t)(tap*64 + coh*32 + ct*16 + l15)*64 + q*8;
                bf16x8 blo = *(const bf16x8*)wp;
                bf16x8 bhi = *(const bf16x8*)(wp + 32);
                o[ct] = MFMA16(alo, blo, o[ct]);
                o[ct] = MFMA16(ahi, bhi, o[ct]);
            }
        }
    }
    #pragma unroll
    for (int ct = 0; ct < 2; ++ct) {
        int co = coh*32 + ct*16 + l15;
        float bias = b2v[co];
        #pragma unroll
        for (int r = 0; r < 4; ++r)
            As[pxg*16 + q*4 + r][co] = (bf16)fmaxf(o[ct][r] + bias, 0.f);
    }
    __syncthreads();

    // conv3 1x1: wave handles its 16 px, co-half coh
    bf16x8 blo = *(const bf16x8*)&As[pxg*16 + l15][q*8];
    bf16x8 bhi = *(const bf16x8*)&As[pxg*16 + l15][32 + q*8];
    f32x4 o3[2];
    #pragma unroll
    for (int mt = 0; mt < 2; ++mt) {
        const bf16* ap = W3 + (size_t)(coh*32 + mt*16 + l15)*64 + q*8;
        bf16x8 alo = *(const bf16x8*)ap;
        bf16x8 ahi = *(const bf16x8*)(ap + 32);
        f32x4 s = MFMA16(alo, blo, zero4());
        o3[mt] = MFMA16(ahi, bhi, s);
    }
    int pbase = y*128 + xq*32 + pxg*16 + l15;
    #pragma unroll
    for (int mt = 0; mt < 2; ++mt) {
        #pragma unroll
        for (int r = 0; r < 4; ++r) {
            int co = coh*32 + mt*16 + q*4 + r;
            size_t idx = (size_t)co*HW + pbase;
            out[idx] = x[idx] + b3[co] + o3[mt][r];
        }
    }
}

extern "C" void kernel_launch(void* const* d_in, const int* in_sizes, int n_in,
                              void* d_out, int out_size, void* d_ws, size_t ws_size,
                              hipStream_t stream) {
    (void)in_sizes; (void)n_in; (void)out_size; (void)ws_size;
    const float* x    = (const float*)d_in[0];
    const float* unet = (const float*)d_in[1];
    const float* wqk  = (const float*)d_in[2];
    const float* c1w  = (const float*)d_in[3];
    const float* c1b  = (const float*)d_in[4];
    const float* c2w  = (const float*)d_in[5];
    const float* c2b  = (const float*)d_in[6];
    const float* c3w  = (const float*)d_in[7];
    const float* c3b  = (const float*)d_in[8];
    const float* clw  = (const float*)d_in[9];
    const float* clb  = (const float*)d_in[10];
    float* out = (float*)d_out;

    char* ws = (char*)d_ws;
    bf16*  Q     = (bf16*)(ws + OFF_Q);
    bf16*  T     = (bf16*)(ws + OFF_T);
    bf16*  T2    = (bf16*)(ws + OFF_T2);
    bf16*  W1    = (bf16*)(ws + OFF_W1);
    bf16*  W2    = (bf16*)(ws + OFF_W2);
    bf16*  W3    = (bf16*)(ws + OFF_W3);
    bf16*  WLb   = (bf16*)(ws + OFF_WL);

    k_qv<<<dim3(832),      dim3(256), 0, stream>>>(x, wqk, c1w, c2w, c3w, clw, Q,
                                                   W1, W2, W3, WLb);
    k_g2convl<<<dim3(256), dim3(256), 0, stream>>>(Q, unet, x, WLb, clw, clb, T);
    k_conv3x3<<<dim3(512), dim3(256), 0, stream>>>(T, W1, c1b, T2, 1);
    k_conv23<<<dim3(512),  dim3(256), 0, stream>>>(T2, W2, c2b, W3, c3b, x, out);
}

// Round 4
// 121.943 us; speedup vs baseline: 3.0961x; 1.2972x over previous
//
#include <hip/hip_runtime.h>

typedef __bf16 bf16;
typedef bf16 bf16x8 __attribute__((ext_vector_type(8)));
typedef bf16 bf16x4 __attribute__((ext_vector_type(4)));
typedef float f32x4 __attribute__((ext_vector_type(4)));

#define MFMA16(a,b,c) __builtin_amdgcn_mfma_f32_16x16x32_bf16(a,b,c,0,0,0)

__device__ inline f32x4 zero4() { f32x4 z; z[0]=0.f; z[1]=0.f; z[2]=0.f; z[3]=0.f; return z; }

#define HW 16384   // 128*128
#define NQ 4096    // positions per window

// ---- workspace layout (bytes) ----
constexpr size_t OFF_Q    = 4096;                              // bf16 (4,4096,64)  2 MB  (row-major)
constexpr size_t OFF_QT   = OFF_Q  + (size_t)2097152;          // bf16 (4,64,4096)  2 MB  (Q^T)
constexpr size_t OFF_VT   = OFF_QT + (size_t)2097152;          // bf16 (4,64,4096)  2 MB
constexpr size_t OFF_MF   = OFF_VT + (size_t)2097152;          // fp32 (4,80,80) final M (atomic acc)
constexpr size_t OFF_T    = OFF_MF + (size_t)131072;           // bf16 HWC 2 MB
constexpr size_t OFF_T2   = OFF_T  + (size_t)2097152;          // bf16 HWC 2 MB
constexpr size_t OFF_W1   = OFF_T2 + (size_t)2097152;          // bf16 (9,64,64)
constexpr size_t OFF_W2   = OFF_W1 + 73728;
constexpr size_t OFF_W3   = OFF_W2 + 73728;                    // bf16 (64,64)
constexpr size_t OFF_WL   = OFF_W3 + 8192;                     // bf16 (64,64) convl weight

// ---------- K1: Q = normalize(x@wqk) via MFMA (x split hi/lo bf16, W bf16);
// ----------     writes Q, Q^T, V^T; zeroes Mf. 512 blocks. ----------
__global__ __launch_bounds__(256) void k_qv(const float* __restrict__ x, const float* __restrict__ wqk,
                                            bf16* __restrict__ Q, bf16* __restrict__ Qt,
                                            bf16* __restrict__ Vt, float* __restrict__ Mf) {
    int t = threadIdx.x, bx = blockIdx.x;
    int y = bx >> 2, x0 = (bx & 3) * 32;
    __shared__ __align__(16) bf16 xhi[32][72];   // [px][c]
    __shared__ __align__(16) bf16 xlo[32][72];
    __shared__ __align__(16) bf16 Wt[64][72];    // [e][c]  (wqk transposed)
    __shared__ bf16 qts[64][34];                 // [e][px]
    __shared__ float ssp[2][32];                 // per-e-half partial sumsq [eh][px]

    if (bx < 25) {     // zero the atomic M accumulator (25600 floats)
        int i = bx*1024 + t*4;
        if (i < 25600) {
            float4 z; z.x = 0.f; z.y = 0.f; z.z = 0.f; z.w = 0.f;
            *(float4*)(Mf + i) = z;
        }
    }

    // load 32 pixels x 64 channels; write Vt on the way; stage x as hi/lo bf16
    {
        int c = t >> 2, seg = t & 3;
        const float4* xp = (const float4*)(x + (size_t)c*HW + y*128 + x0 + seg*8);
        float f[8];
        float4 v0 = xp[0], v1 = xp[1];
        f[0]=v0.x; f[1]=v0.y; f[2]=v0.z; f[3]=v0.w;
        f[4]=v1.x; f[5]=v1.y; f[6]=v1.z; f[7]=v1.w;
        #pragma unroll
        for (int k = 0; k < 8; ++k) {
            int px = seg*8 + k;
            bf16 h = (bf16)f[k];
            xhi[px][c] = h;
            xlo[px][c] = (bf16)(f[k] - (float)h);
        }
        int dh = y & 1;
        int base_n = (y >> 1)*64 + ((x0 + seg*8) >> 1);
        bf16x4 ve, vo;
        #pragma unroll
        for (int j = 0; j < 4; ++j) { ve[j] = (bf16)f[2*j]; vo[j] = (bf16)f[2*j+1]; }
        *(bf16x4*)(Vt + ((size_t)((dh*2 + 0)*64 + c))*NQ + base_n) = ve;
        *(bf16x4*)(Vt + ((size_t)((dh*2 + 1)*64 + c))*NQ + base_n) = vo;
    }
    // stage Wt[e][c] = bf16(wqk[c][e])  (transpose, bf16)
    {
        int c = t >> 2, e0 = (t & 3) * 16;
        const float4* wp = (const float4*)wqk;
        #pragma unroll
        for (int k = 0; k < 4; ++k) {
            float4 v = wp[t*4 + k];                 // wqk[c][e0+4k .. +4]
            Wt[e0 + k*4 + 0][c] = (bf16)v.x;
            Wt[e0 + k*4 + 1][c] = (bf16)v.y;
            Wt[e0 + k*4 + 2][c] = (bf16)v.z;
            Wt[e0 + k*4 + 3][c] = (bf16)v.w;
        }
    }
    __syncthreads();

    int w = t >> 6, lane = t & 63, q = lane >> 4, l15 = lane & 15;
    int ph = w & 1, eh = w >> 1;     // wave = (px-half, e-half)

    // qk tile: D[px=ph*16+(q*4+r)][e=eh*32+et*16+l15]
    bf16x8 ahf[2], alf[2];
    #pragma unroll
    for (int kf = 0; kf < 2; ++kf) {
        ahf[kf] = *(const bf16x8*)&xhi[ph*16 + l15][kf*32 + q*8];
        alf[kf] = *(const bf16x8*)&xlo[ph*16 + l15][kf*32 + q*8];
    }
    f32x4 acc[2];
    #pragma unroll
    for (int et = 0; et < 2; ++et) {
        acc[et] = zero4();
        #pragma unroll
        for (int kf = 0; kf < 2; ++kf) {
            bf16x8 b = *(const bf16x8*)&Wt[eh*32 + et*16 + l15][kf*32 + q*8];
            acc[et] = MFMA16(ahf[kf], b, acc[et]);
            acc[et] = MFMA16(alf[kf], b, acc[et]);
        }
    }
    // partial sum-of-squares over this wave's 32 e's, per px row
    #pragma unroll
    for (int r = 0; r < 4; ++r) {
        float ss = acc[0][r]*acc[0][r] + acc[1][r]*acc[1][r];
        ss += __shfl_xor(ss, 1);
        ss += __shfl_xor(ss, 2);
        ss += __shfl_xor(ss, 4);
        ss += __shfl_xor(ss, 8);
        if (l15 == 0) ssp[eh][ph*16 + q*4 + r] = ss;
    }
    __syncthreads();

    // combine halves, normalize, write qts[e][px]
    #pragma unroll
    for (int r = 0; r < 4; ++r) {
        int px = ph*16 + q*4 + r;
        float inv = 1.f / (sqrtf(ssp[0][px] + ssp[1][px]) + 1e-8f);
        #pragma unroll
        for (int et = 0; et < 2; ++et)
            qts[eh*32 + et*16 + l15][px] = (bf16)(acc[et][r]*inv);
    }
    __syncthreads();

    // Q row-major write from qts (same indexing as verified round-0 store)
    {
        int p = t >> 3, eg = t & 7;
        bf16x8 qv;
        #pragma unroll
        for (int k = 0; k < 8; ++k) qv[k] = qts[eg*8 + k][p];
        int xp2 = x0 + p;
        int b2 = (y & 1)*2 + (xp2 & 1);
        int nidx = (y >> 1)*64 + (xp2 >> 1);
        *(bf16x8*)(Q + ((size_t)b2*NQ + nidx)*64 + eg*8) = qv;
    }
    // transpose write: Q^T[b2][e][n] (unchanged)
    {
        int e = t >> 2, par = (t >> 1) & 1, seg2 = t & 1;
        int b2w = (y & 1)*2 + par;
        int nbase = (y >> 1)*64 + (x0 >> 1) + seg2*8;
        bf16x8 qt;
        #pragma unroll
        for (int j = 0; j < 8; ++j) qt[j] = qts[e][par + 2*(seg2*8 + j)];
        *(bf16x8*)(Qt + ((size_t)b2w*64 + e)*NQ + nbase) = qt;
    }
}

// ---------- K2: M = [V|1]^T [Qhat|1]  (80x80, K 16-split, atomicAdd into Mf), 64 blocks
// ----------     + weight prep on blocks 64..383 ----------
__global__ __launch_bounds__(256) void k_gemm1(const bf16* __restrict__ Vt, const bf16* __restrict__ Qt,
                                               float* __restrict__ Mf,
                                               const float* __restrict__ w1, const float* __restrict__ w2,
                                               const float* __restrict__ w3, const float* __restrict__ wlc,
                                               bf16* __restrict__ W1, bf16* __restrict__ W2,
                                               bf16* __restrict__ W3, bf16* __restrict__ WLb) {
    int tid = threadIdx.x, bx = blockIdx.x;
    if (bx >= 64) {             // weight prep: 320 blocks
        int g = (bx - 64) * 256 + tid;
        if (g < 36864) {
            int tap = g >> 12, co = (g >> 6) & 63, ci = g & 63;
            W1[g] = (bf16)w1[(co*64 + ci)*9 + tap];
        } else if (g < 73728) {
            int d = g - 36864;
            int tap = d >> 12, co = (d >> 6) & 63, ci = d & 63;
            W2[d] = (bf16)w2[(co*64 + ci)*9 + tap];
        } else if (g < 77824) {
            int d = g - 73728;
            W3[d] = (bf16)w3[d];
        } else if (g < 81920) {
            int d = g - 77824;
            WLb[d] = (bf16)wlc[(d >> 6)*65 + (d & 63)];
        }
        return;
    }
    int b2 = bx & 3, kc = bx >> 2;     // kc 0..15
    int w = tid >> 6, lane = tid & 63, q = lane >> 4, l15 = lane & 15;
    const bf16* Vb  = Vt + (size_t)b2*64*NQ;
    const bf16* Qtb = Qt + (size_t)b2*64*NQ;
    bf16x8 onesfrag = {};
    if (l15 == 0) {
        #pragma unroll
        for (int k = 0; k < 8; ++k) onesfrag[k] = (bf16)1.0f;
    }
    f32x4 acc[5], acc1[5];
    #pragma unroll
    for (int nt = 0; nt < 5; ++nt) { acc[nt] = zero4(); acc1[nt] = zero4(); }

    int k0 = kc*256 + q*8;
    for (int it = 0; it < 8; ++it) {
        int kk = k0 + it*32;
        bf16x8 av = *(const bf16x8*)(Vb + (size_t)(w*16 + l15)*NQ + kk);
        bf16x8 b[5];
        #pragma unroll
        for (int nt = 0; nt < 4; ++nt) b[nt] = *(const bf16x8*)(Qtb + (size_t)(nt*16 + l15)*NQ + kk);
        b[4] = onesfrag;                               // col 64 = ones (c0 / m1)
        #pragma unroll
        for (int nt = 0; nt < 5; ++nt) {
            acc[nt] = MFMA16(av, b[nt], acc[nt]);
            if (w == 0) acc1[nt] = MFMA16(onesfrag, b[nt], acc1[nt]);  // row 64 = colsums
        }
    }
    float* mp = Mf + (size_t)b2*6400;
    #pragma unroll
    for (int nt = 0; nt < 5; ++nt)
        #pragma unroll
        for (int r = 0; r < 4; ++r)
            if (nt < 4 || l15 == 0)
                unsafeAtomicAdd(&mp[(w*16 + q*4 + r)*80 + nt*16 + l15], acc[nt][r]);
    if (w == 0 && q == 0) {
        #pragma unroll
        for (int nt = 0; nt < 5; ++nt)
            if (nt < 4 || l15 == 0)
                unsafeAtomicAdd(&mp[64*80 + nt*16 + l15], acc1[nt][0]);
    }
}

// ---------- K3: fused gemm2 (attn tile) + convl (65->64 1x1) + x -> T (HWC bf16) ----------
__global__ __launch_bounds__(256) void k_g2convl(const bf16* __restrict__ Q, const float* __restrict__ Mf,
                                                 const float* __restrict__ unet, const float* __restrict__ x,
                                                 const bf16* __restrict__ WLb, const float* __restrict__ wl,
                                                 const float* __restrict__ bl, bf16* __restrict__ T) {
    int t = threadIdx.x, bx = blockIdx.x;   // bx = pixel-block = (n & 255)
    int p0 = bx * 64;
    __shared__ __align__(16) bf16 Msl[4][80][88];
    __shared__ __align__(16) bf16 As[64][72];   // [px(=value ch)][ci(=attn ch)]

    #pragma unroll
    for (int ii = 0; ii < 25; ++ii) {
        int i = ii*1024 + t*4;
        float4 v = *(const float4*)(Mf + i);
        int b2i = i / 6400, rem = i - b2i*6400;
        int rr = rem / 80, cc = rem - rr*80;
        bf16x4 pk; pk[0] = (bf16)v.x; pk[1] = (bf16)v.y; pk[2] = (bf16)v.z; pk[3] = (bf16)v.w;
        *(bf16x4*)&Msl[b2i][rr][cc] = pk;
    }
    __syncthreads();

    int w = t >> 6, lane = t & 63, q = lane >> 4, l15 = lane & 15;
    {   // stage 1: attn tile. wave w = window b2; A rows n = m*256 + bx (m = l15)
        int b2 = w;
        const bf16* qp = Q + ((size_t)b2*NQ + l15*256 + bx)*64 + q*8;
        bf16x8 a0 = *(const bf16x8*)qp;
        bf16x8 a1 = *(const bf16x8*)(qp + 32);
        f32x4 acc[5];
        #pragma unroll
        for (int ct = 0; ct < 5; ++ct) {
            bf16x8 bf0 = *(const bf16x8*)&Msl[b2][ct*16 + l15][q*8];
            bf16x8 bf1 = *(const bf16x8*)&Msl[b2][ct*16 + l15][32 + q*8];
            f32x4 s = MFMA16(a0, bf0, zero4());
            acc[ct] = MFMA16(a1, bf1, s);
        }
        float c0v[4];
        #pragma unroll
        for (int ct = 0; ct < 4; ++ct) c0v[ct] = (float)Msl[b2][ct*16 + l15][64];
        #pragma unroll
        for (int r = 0; r < 4; ++r) {
            float ldot = __shfl(acc[4][r], lane & 48);
            float rl = 1.0f / fmaf(ldot, 0.125f, 4096.0f);
            #pragma unroll
            for (int ct = 0; ct < 4; ++ct)
                As[ct*16 + l15][b2*16 + q*4 + r] = (bf16)(fmaf(acc[ct][r], 0.125f, c0v[ct]) * rl);
        }
    }
    __syncthreads();

    // stage 2: convl — wave w = px-block (n = w*16+l15); A = WLb rows (m = co) -> co in regs,
    // contiguous bf16x4 stores to T
    int px = w*16 + l15;
    bf16x8 b0 = *(const bf16x8*)&As[px][q*8];
    bf16x8 b1 = *(const bf16x8*)&As[px][32 + q*8];
    float u = unet[p0 + px];
    #pragma unroll
    for (int mt = 0; mt < 4; ++mt) {
        const bf16* ap = WLb + (size_t)(mt*16 + l15)*64 + q*8;
        bf16x8 a0 = *(const bf16x8*)ap;
        bf16x8 a1 = *(const bf16x8*)(ap + 32);
        f32x4 s = MFMA16(a0, b0, zero4());
        f32x4 o = MFMA16(a1, b1, s);
        bf16x4 st;
        #pragma unroll
        for (int r = 0; r < 4; ++r) {
            int co = mt*16 + q*4 + r;
            float v = o[r] + u*wl[co*65 + 64] + bl[co] + x[(size_t)co*HW + p0 + px];
            st[r] = (bf16)v;
        }
        *(bf16x4*)(T + (size_t)(p0 + px)*64 + mt*16 + q*4) = st;
    }
}

// ---------- K4: conv1 3x3 dil1 + bias + relu, HWC bf16 -> HWC bf16, co 2-way, LDS weights ----------
__global__ __launch_bounds__(256, 2) void k_conv3x3(const bf16* __restrict__ IN, const bf16* __restrict__ WT,
                                                    const float* __restrict__ B, bf16* __restrict__ OUT,
                                                    int dil) {
    int tid = threadIdx.x, bx = blockIdx.x;
    int y = bx >> 2, xh = (bx >> 1) & 1, coh = bx & 1;
    int w = tid >> 6, lane = tid & 63, q = lane >> 4, l15 = lane & 15;
    int xb = xh*64 + w*16;

    __shared__ __align__(16) bf16 wsl[9][32][72];
    for (int i = tid; i < 2304; i += 256) {
        int tap = i >> 8, rem = i & 255, co = rem >> 3, k8 = (rem & 7) * 8;
        *(bf16x8*)&wsl[tap][co][k8] =
            *(const bf16x8*)(WT + (((size_t)(tap*64 + coh*32 + co)) << 6) + k8);
    }
    __syncthreads();

    f32x4 o[2];
    o[0] = zero4(); o[1] = zero4();
    #pragma unroll
    for (int ky = 0; ky < 3; ++ky) {
        int yy = y + (ky - 1)*dil;
        bool yok = (yy >= 0) && (yy < 128);
        #pragma unroll
        for (int kx = 0; kx < 3; ++kx) {
            int xx = xb + l15 + (kx - 1)*dil;
            bool ok = yok && (xx >= 0) && (xx < 128);
            bf16x8 alo = {}, ahi = {};
            if (ok) {
                const bf16* ip = IN + (size_t)(yy*128 + xx)*64 + q*8;
                alo = *(const bf16x8*)ip;
                ahi = *(const bf16x8*)(ip + 32);
            }
            int tap = ky*3 + kx;
            #pragma unroll
            for (int ct = 0; ct < 2; ++ct) {
                bf16x8 blo = *(const bf16x8*)&wsl[tap][ct*16 + l15][q*8];
                bf16x8 bhi = *(const bf16x8*)&wsl[tap][ct*16 + l15][32 + q*8];
                o[ct] = MFMA16(alo, blo, o[ct]);
                o[ct] = MFMA16(ahi, bhi, o[ct]);
            }
        }
    }
    #pragma unroll
    for (int ct = 0; ct < 2; ++ct) {
        int co = coh*32 + ct*16 + l15;
        float bias = B[co];
        #pragma unroll
        for (int r = 0; r < 4; ++r) {
            float v = fmaxf(o[ct][r] + bias, 0.f);
            OUT[(size_t)(y*128 + xb + q*4 + r)*64 + co] = (bf16)v;
        }
    }
}

// ---------- K5: fused conv2 (3x3 dil2, relu) + conv3 (1x1) + x -> out (CHW fp32) ----------
__global__ __launch_bounds__(256) void k_conv23(const bf16* __restrict__ IN, const bf16* __restrict__ W2T,
                                                const float* __restrict__ b2v, const bf16* __restrict__ W3,
                                                const float* __restrict__ b3, const float* __restrict__ x,
                                                float* __restrict__ out) {
    int tid = threadIdx.x, bx = blockIdx.x;
    int y = bx >> 2, xq = bx & 3;
    int w = tid >> 6, lane = tid & 63, q = lane >> 4, l15 = lane & 15;
    int pxg = w & 1, coh = w >> 1;
    int xb = xq*32 + pxg*16;

    __shared__ __align__(16) bf16 As[32][72];   // [px-in-block][co]

    f32x4 o[2];
    o[0] = zero4(); o[1] = zero4();
    #pragma unroll
    for (int ky = 0; ky < 3; ++ky) {
        int yy = y + (ky - 1)*2;
        bool yok = (yy >= 0) && (yy < 128);
        #pragma unroll
        for (int kx = 0; kx < 3; ++kx) {
            int xx = xb + l15 + (kx - 1)*2;
            bool ok = yok && (xx >= 0) && (xx < 128);
            bf16x8 alo = {}, ahi = {};
            if (ok) {
                const bf16* ip = IN + (size_t)(yy*128 + xx)*64 + q*8;
                alo = *(const bf16x8*)ip;
                ahi = *(const bf16x8*)(ip + 32);
            }
            int tap = ky*3 + kx;
            #pragma unroll
            for (int ct = 0; ct < 2; ++ct) {
                const bf16* wp = W2T + (size_t)(tap*64 + coh*32 + ct*16 + l15)*64 + q*8;
                bf16x8 blo = *(const bf16x8*)wp;
                bf16x8 bhi = *(const bf16x8*)(wp + 32);
                o[ct] = MFMA16(alo, blo, o[ct]);
                o[ct] = MFMA16(ahi, bhi, o[ct]);
            }
        }
    }
    #pragma unroll
    for (int ct = 0; ct < 2; ++ct) {
        int co = coh*32 + ct*16 + l15;
        float bias = b2v[co];
        #pragma unroll
        for (int r = 0; r < 4; ++r)
            As[pxg*16 + q*4 + r][co] = (bf16)fmaxf(o[ct][r] + bias, 0.f);
    }
    __syncthreads();

    // conv3 1x1: wave handles its 16 px, co-half coh
    bf16x8 blo = *(const bf16x8*)&As[pxg*16 + l15][q*8];
    bf16x8 bhi = *(const bf16x8*)&As[pxg*16 + l15][32 + q*8];
    f32x4 o3[2];
    #pragma unroll
    for (int mt = 0; mt < 2; ++mt) {
        const bf16* ap = W3 + (size_t)(coh*32 + mt*16 + l15)*64 + q*8;
        bf16x8 alo = *(const bf16x8*)ap;
        bf16x8 ahi = *(const bf16x8*)(ap + 32);
        f32x4 s = MFMA16(alo, blo, zero4());
        o3[mt] = MFMA16(ahi, bhi, s);
    }
    int pbase = y*128 + xq*32 + pxg*16 + l15;
    #pragma unroll
    for (int mt = 0; mt < 2; ++mt) {
        #pragma unroll
        for (int r = 0; r < 4; ++r) {
            int co = coh*32 + mt*16 + q*4 + r;
            size_t idx = (size_t)co*HW + pbase;
            out[idx] = x[idx] + b3[co] + o3[mt][r];
        }
    }
}

extern "C" void kernel_launch(void* const* d_in, const int* in_sizes, int n_in,
                              void* d_out, int out_size, void* d_ws, size_t ws_size,
                              hipStream_t stream) {
    (void)in_sizes; (void)n_in; (void)out_size; (void)ws_size;
    const float* x    = (const float*)d_in[0];
    const float* unet = (const float*)d_in[1];
    const float* wqk  = (const float*)d_in[2];
    const float* c1w  = (const float*)d_in[3];
    const float* c1b  = (const float*)d_in[4];
    const float* c2w  = (const float*)d_in[5];
    const float* c2b  = (const float*)d_in[6];
    const float* c3w  = (const float*)d_in[7];
    const float* c3b  = (const float*)d_in[8];
    const float* clw  = (const float*)d_in[9];
    const float* clb  = (const float*)d_in[10];
    float* out = (float*)d_out;

    char* ws = (char*)d_ws;
    bf16*  Q     = (bf16*)(ws + OFF_Q);
    bf16*  Qt    = (bf16*)(ws + OFF_QT);
    bf16*  Vt    = (bf16*)(ws + OFF_VT);
    float* Mf    = (float*)(ws + OFF_MF);
    bf16*  T     = (bf16*)(ws + OFF_T);
    bf16*  T2    = (bf16*)(ws + OFF_T2);
    bf16*  W1    = (bf16*)(ws + OFF_W1);
    bf16*  W2    = (bf16*)(ws + OFF_W2);
    bf16*  W3    = (bf16*)(ws + OFF_W3);
    bf16*  WLb   = (bf16*)(ws + OFF_WL);

    k_qv<<<dim3(512),     dim3(256), 0, stream>>>(x, wqk, Q, Qt, Vt, Mf);
    k_gemm1<<<dim3(384),  dim3(256), 0, stream>>>(Vt, Qt, Mf, c1w, c2w, c3w, clw,
                                                  W1, W2, W3, WLb);
    k_g2convl<<<dim3(256), dim3(256), 0, stream>>>(Q, Mf, unet, x, WLb, clw, clb, T);
    k_conv3x3<<<dim3(512), dim3(256), 0, stream>>>(T, W1, c1b, T2, 1);
    k_conv23<<<dim3(512),  dim3(256), 0, stream>>>(T2, W2, c2b, W3, c3b, x, out);
}